// Round 5
// baseline (650.532 us; speedup 1.0000x reference)
//
#include <hip/hip_runtime.h>

#define N_NODES 65536
#define N_EDGES 262144
#define NPB 32   // dst nodes per block in iter_kernel (8 per wave, 4 waves)

// ---------------- setup kernels ----------------

// V[j] = sum_{k: w1[k]>0} w1[k]*w2[k][j];  Btot[j] = sum_{k: w1[k]>0} b1[k]*w2[k][j] + b2[j]
// exact linearization of relu(a*w1+b1)@w2+b2 for b1==0, a>=0.
__global__ void vmat_kernel(const float* __restrict__ w1, const float* __restrict__ b1,
                            const float* __restrict__ w2, const float* __restrict__ b2,
                            float* __restrict__ V, float* __restrict__ Btot, int* __restrict__ flag) {
    int j = blockIdx.x * 256 + threadIdx.x;        // 0..1023
    float v = 0.0f, c0 = 0.0f;
#pragma unroll
    for (int k = 0; k < 64; ++k) {
        float w = w1[k];
        if (w > 0.0f) {
            float wv = w2[k * 1024 + j];
            v += w * wv;
            c0 += b1[k] * wv;
        }
    }
    V[j] = v;
    float bt = c0 + b2[j];
    Btot[j] = bt;
    if (bt != 0.0f) atomicOr(flag, 1);
}

// h0 = relu(x@w0+b0); P0 = h0@V; Q0 = h0@Btot (if flag). 8 nodes / 256-thread block.
__global__ __launch_bounds__(256) void lin0proj_kernel(
    const float* __restrict__ x, const float* __restrict__ w0, const float* __restrict__ b0,
    const float* __restrict__ V, const float* __restrict__ Btot, const int* __restrict__ flag,
    float* __restrict__ h, float* __restrict__ P, float* __restrict__ Q) {
    __shared__ float Vl[1024];
    __shared__ float xs[8][11];
    __shared__ float hs[8][32];
    int t = threadIdx.x;
    for (int i = t; i < 1024; i += 256) Vl[i] = V[i];
    int j = t & 31, g = t >> 5;
    int n = blockIdx.x * 8 + g;
    if (j < 11) xs[g][j] = x[n * 11 + j];
    __syncthreads();
    float acc = b0[j];
#pragma unroll
    for (int i = 0; i < 11; ++i) acc += xs[g][i] * w0[i * 32 + j];
    float hv = fmaxf(acc, 0.0f);
    h[n * 32 + j] = hv;
    hs[g][j] = hv;
    __syncthreads();
    float p = 0.0f;
#pragma unroll
    for (int i = 0; i < 32; ++i) p += hs[g][i] * Vl[i * 32 + j];
    P[n * 32 + j] = p;
    if (flag[0] != 0) {
        float q = 0.0f;
        for (int i = 0; i < 32; ++i) q += hs[g][i] * Btot[i * 32 + j];
        Q[n * 32 + j] = q;
    }
}

__global__ void hist_kernel(const int* __restrict__ dst, int* __restrict__ counts) {
    int e = blockIdx.x * 256 + threadIdx.x;
    if (e < N_EDGES) atomicAdd(&counts[dst[e]], 1);
}

// single-block exclusive scan of counts[65536] -> offs, offs[N]=E
__global__ void scan_kernel(const int* __restrict__ counts, int* __restrict__ offs) {
    __shared__ int part[1024];
    int t = threadIdx.x;
    int base = t * 64;
    int s = 0;
    for (int i = 0; i < 64; ++i) s += counts[base + i];
    part[t] = s;
    __syncthreads();
    for (int off = 1; off < 1024; off <<= 1) {
        int v = part[t];
        int add = (t >= off) ? part[t - off] : 0;
        __syncthreads();
        part[t] = v + add;
        __syncthreads();
    }
    int run = (t == 0) ? 0 : part[t - 1];
    for (int i = 0; i < 64; ++i) { offs[base + i] = run; run += counts[base + i]; }
    if (t == 1023) offs[N_NODES] = run;
}

__global__ void inv_kernel(const int* __restrict__ counts, float* __restrict__ inv) {
    int n = blockIdx.x * 256 + threadIdx.x;
    int c = counts[n];
    inv[n] = (c > 0) ? (1.0f / (float)c) : 0.0f;
}

// bucket edges by dst; rec = (src | dstLocal<<16, attr*inv[dst]); qc = inv[dst]
__global__ void fill_kernel(const int* __restrict__ src, const int* __restrict__ dst,
                            const float* __restrict__ attr, const int* __restrict__ offs,
                            const float* __restrict__ inv, int* __restrict__ cursor,
                            int2* __restrict__ edgeRec, float* __restrict__ qc) {
    int e = blockIdx.x * 256 + threadIdx.x;
    if (e >= N_EDGES) return;
    int d = dst[e];
    int p = offs[d] + atomicAdd(&cursor[d], 1);
    edgeRec[p] = make_int2(src[e] | ((d & (NPB - 1)) << 16), __float_as_int(attr[e] * inv[d]));
    qc[p] = inv[d];
}

// ---------------- fused per-iteration kernel ----------------
// Wave owns 8 consecutive dst nodes => its CSR slice is contiguous AND its
// aggS rows are private to the wave (no cross-wave LDS collisions, no
// barrier between edge and node phase). Edge phase is a flat 8-edge/iter
// pipelined loop: next iteration's records prefetched while current P-row
// gathers are in flight (~8 independent loads in flight per wave).
__global__ __launch_bounds__(256, 8) void iter_kernel(
    float* __restrict__ h, const float* __restrict__ Pc, float* __restrict__ Pn,
    const float* __restrict__ Qc, float* __restrict__ Qn,
    const int* __restrict__ offs, const int2* __restrict__ edgeRec,
    const float* __restrict__ qc, const float* __restrict__ V,
    const float* __restrict__ Btot, const float* __restrict__ root,
    const float* __restrict__ bias, const int* __restrict__ flag) {
    __shared__ float Vl[1024], Rl[1024];
    __shared__ float aggS[NPB * 32];
    __shared__ float hrow[NPB][32];
    int t = threadIdx.x;
    bool useB = (flag[0] != 0);
    for (int i = t; i < 1024; i += 256) { Vl[i] = V[i]; Rl[i] = root[i]; }
    for (int i = t; i < NPB * 32; i += 256) aggS[i] = 0.0f;
    int lane = t & 63, w = t >> 6;
    int j = lane & 31, half = lane >> 5;
    int base = blockIdx.x * NPB;
    int nodeBeg = base + w * 8;
    float bj = bias[j];
    __syncthreads();   // aggS zeroing is cross-wave; everything after is wave-private

    int wbeg = offs[nodeBeg];
    int wend = offs[nodeBeg + 8];

    if (wbeg < wend) {
        int pb = wbeg;
        int2 rec[4];
#pragma unroll
        for (int k = 0; k < 4; ++k) {
            int idx = pb + half + 2 * k;
            rec[k] = edgeRec[min(idx, wend - 1)];
        }
        while (pb < wend) {
            int npb = pb + 8;
            int2 cur[4];
#pragma unroll
            for (int k = 0; k < 4; ++k) cur[k] = rec[k];
            if (npb < wend) {
#pragma unroll
                for (int k = 0; k < 4; ++k) {
                    int idx = npb + half + 2 * k;
                    rec[k] = edgeRec[min(idx, wend - 1)];
                }
            }
#pragma unroll
            for (int k = 0; k < 4; ++k) {
                int idx = pb + half + 2 * k;
                int sx = cur[k].x & 0xffff;
                int dl = (cur[k].x >> 16) & (NPB - 1);
                float m = __int_as_float(cur[k].y) * Pc[sx * 32 + j];
                m = (idx < wend) ? m : 0.0f;
                atomicAdd(&aggS[dl * 32 + j], m);
            }
            pb = npb;
        }
        if (useB) {   // generality path (flag==0 for this input): slow second pass
            for (int p = wbeg + half; p < wend; p += 2) {
                int2 r0 = edgeRec[p];
                int sx = r0.x & 0xffff;
                int dl = (r0.x >> 16) & (NPB - 1);
                atomicAdd(&aggS[dl * 32 + j], qc[p] * Qc[sx * 32 + j]);
            }
        }
    }

    // ---- node phase: half-wave owns 4 full nodes; LDS float4 broadcast matvecs
#pragma unroll
    for (int rr = 0; rr < 4; ++rr) {
        int ln = (w << 3) + (half << 2) + rr;
        int n = base + ln;
        float hv = h[n * 32 + j];
        hrow[ln][j] = hv;
        float mv = bj;
#pragma unroll
        for (int i = 0; i < 32; i += 4) {
            float4 h4 = *(const float4*)&hrow[ln][i];
            mv += h4.x * Rl[i * 32 + j] + h4.y * Rl[(i + 1) * 32 + j]
                + h4.z * Rl[(i + 2) * 32 + j] + h4.w * Rl[(i + 3) * 32 + j];
        }
        float hnew = hv + fmaxf(aggS[ln * 32 + j] + mv, 0.0f);
        h[n * 32 + j] = hnew;
        hrow[ln][j] = hnew;
        float pvv = 0.0f;
#pragma unroll
        for (int i = 0; i < 32; i += 4) {
            float4 h4 = *(const float4*)&hrow[ln][i];
            pvv += h4.x * Vl[i * 32 + j] + h4.y * Vl[(i + 1) * 32 + j]
                 + h4.z * Vl[(i + 2) * 32 + j] + h4.w * Vl[(i + 3) * 32 + j];
        }
        Pn[n * 32 + j] = pvv;
        if (useB) {
            float qv = 0.0f;
            for (int i = 0; i < 32; ++i) qv += hrow[ln][i] * Btot[i * 32 + j];
            Qn[n * 32 + j] = qv;
        }
    }
}

// ---------------- final reduction ----------------

__global__ void reduce_kernel(const float* __restrict__ h, float* __restrict__ gacc) {
    int j = threadIdx.x & 31, g = threadIdx.x >> 5;   // g: 0..7
    float s = 0.0f;
    int node0 = blockIdx.x * 128;
    for (int n = node0 + g; n < node0 + 128; n += 8) s += h[n * 32 + j];
    __shared__ float red[8][32];
    red[g][j] = s;
    __syncthreads();
    if (g == 0) {
        float tt = 0.0f;
        for (int k = 0; k < 8; ++k) tt += red[k][j];
        atomicAdd(&gacc[j], tt);
    }
}

__global__ void out_kernel(const float* __restrict__ gacc, const float* __restrict__ w,
                           const float* __restrict__ b, float* __restrict__ out) {
    if (threadIdx.x == 0) {
        float acc = 0.0f;
        for (int j = 0; j < 32; ++j) acc += gacc[j] * w[j];
        out[0] = acc * (1.0f / (float)N_NODES) + b[0];
    }
}

// ---------------- launch ----------------

extern "C" void kernel_launch(void* const* d_in, const int* in_sizes, int n_in,
                              void* d_out, int out_size, void* d_ws, size_t ws_size,
                              hipStream_t stream) {
    (void)in_sizes; (void)n_in; (void)out_size; (void)ws_size;
    const float* x        = (const float*)d_in[0];
    const int*   eidx     = (const int*)d_in[1];
    const float* eattr    = (const float*)d_in[2];
    const float* lin0_w   = (const float*)d_in[3];
    const float* lin0_b   = (const float*)d_in[4];
    const float* nn_w1    = (const float*)d_in[5];
    const float* nn_b1    = (const float*)d_in[6];
    const float* nn_w2    = (const float*)d_in[7];
    const float* nn_b2    = (const float*)d_in[8];
    const float* root     = (const float*)d_in[9];
    const float* conv_b   = (const float*)d_in[10];
    const float* lin2_w   = (const float*)d_in[11];
    const float* lin2_b   = (const float*)d_in[12];
    float* out = (float*)d_out;

    const int* src = eidx;
    const int* dst = eidx + N_EDGES;

    char* ws = (char*)d_ws;
    size_t off = 0;
    float* h    = (float*)(ws + off); off += (size_t)N_NODES * 32 * 4;   // 8 MB
    float* P0   = (float*)(ws + off); off += (size_t)N_NODES * 32 * 4;   // 8 MB
    float* P1   = (float*)(ws + off); off += (size_t)N_NODES * 32 * 4;   // 8 MB
    float* Q0   = (float*)(ws + off); off += (size_t)N_NODES * 32 * 4;   // 8 MB
    float* Q1   = (float*)(ws + off); off += (size_t)N_NODES * 32 * 4;   // 8 MB
    float* V    = (float*)(ws + off); off += 4096;
    float* Btot = (float*)(ws + off); off += 4096;
    float* inv  = (float*)(ws + off); off += (size_t)N_NODES * 4;
    int*   offs = (int*)(ws + off);   off += 262400;                     // (N+1)*4 padded
    int2*  edgeRec = (int2*)(ws + off); off += (size_t)N_EDGES * 8;
    float* qc   = (float*)(ws + off); off += (size_t)N_EDGES * 4;
    // zeroed region: counts | cursor | gacc(32f) | flag
    char*  zbase  = ws + off;
    int*   counts = (int*)zbase;
    int*   cursor = (int*)(zbase + (size_t)N_NODES * 4);
    float* gacc   = (float*)(zbase + (size_t)N_NODES * 8);
    int*   flag   = (int*)(zbase + (size_t)N_NODES * 8 + 128);
    size_t zsize  = (size_t)N_NODES * 8 + 256;

    hipMemsetAsync(zbase, 0, zsize, stream);

    vmat_kernel<<<4, 256, 0, stream>>>(nn_w1, nn_b1, nn_w2, nn_b2, V, Btot, flag);
    lin0proj_kernel<<<N_NODES / 8, 256, 0, stream>>>(x, lin0_w, lin0_b, V, Btot, flag, h, P0, Q0);
    hist_kernel<<<N_EDGES / 256, 256, 0, stream>>>(dst, counts);
    scan_kernel<<<1, 1024, 0, stream>>>(counts, offs);
    inv_kernel<<<N_NODES / 256, 256, 0, stream>>>(counts, inv);
    fill_kernel<<<N_EDGES / 256, 256, 0, stream>>>(src, dst, eattr, offs, inv, cursor, edgeRec, qc);

    float* Pbuf[2] = {P0, P1};
    float* Qbuf[2] = {Q0, Q1};
    for (int it = 0; it < 8; ++it) {
        iter_kernel<<<N_NODES / NPB, 256, 0, stream>>>(
            h, Pbuf[it & 1], Pbuf[(it + 1) & 1], Qbuf[it & 1], Qbuf[(it + 1) & 1],
            offs, edgeRec, qc, V, Btot, root, conv_b, flag);
    }

    reduce_kernel<<<N_NODES / 128, 256, 0, stream>>>(h, gacc);
    out_kernel<<<1, 64, 0, stream>>>(gacc, lin2_w, lin2_b, out);
}

// Round 6
// 360.610 us; speedup vs baseline: 1.8040x; 1.8040x over previous
//
#include <hip/hip_runtime.h>
#include <hip/hip_fp16.h>

#define N_NODES 65536
#define N_EDGES 262144

// ---------------- setup kernels ----------------

// V[j] = sum_{k: w1[k]>0} w1[k]*w2[k][j];  Btot[j] = sum_{k: w1[k]>0} b1[k]*w2[k][j] + b2[j]
// exact linearization of relu(a*w1+b1)@w2+b2 for b1==0, a>=0.
__global__ void vmat_kernel(const float* __restrict__ w1, const float* __restrict__ b1,
                            const float* __restrict__ w2, const float* __restrict__ b2,
                            float* __restrict__ V, float* __restrict__ Btot, int* __restrict__ flag) {
    int j = blockIdx.x * 256 + threadIdx.x;        // 0..1023
    float v = 0.0f, c0 = 0.0f;
#pragma unroll
    for (int k = 0; k < 64; ++k) {
        float w = w1[k];
        if (w > 0.0f) {
            float wv = w2[k * 1024 + j];
            v += w * wv;
            c0 += b1[k] * wv;
        }
    }
    V[j] = v;
    float bt = c0 + b2[j];
    Btot[j] = bt;
    if (bt != 0.0f) atomicOr(flag, 1);
}

// h0 = relu(x @ lin0_w + lin0_b)
__global__ void lin0_kernel(const float* __restrict__ x, const float* __restrict__ w,
                            const float* __restrict__ b, float* __restrict__ h) {
    int idx = blockIdx.x * 256 + threadIdx.x;      // n*32+j
    int n = idx >> 5, j = idx & 31;
    float acc = b[j];
#pragma unroll
    for (int i = 0; i < 11; ++i) acc += x[n * 11 + i] * w[i * 32 + j];
    h[idx] = fmaxf(acc, 0.0f);
}

// histograms by src (CSC) and dst (CSR divisor + segment offsets)
__global__ void hist2_kernel(const int* __restrict__ src, const int* __restrict__ dst,
                             int* __restrict__ countsS, int* __restrict__ countsD) {
    int e = blockIdx.x * 256 + threadIdx.x;
    if (e < N_EDGES) {
        atomicAdd(&countsS[src[e]], 1);
        atomicAdd(&countsD[dst[e]], 1);
    }
}

// grid=2: block 0 scans countsS->offsS, block 1 scans countsD->offsD
__global__ void scan2_kernel(const int* __restrict__ countsS, const int* __restrict__ countsD,
                             int* __restrict__ offsS, int* __restrict__ offsD) {
    const int* counts = blockIdx.x ? countsD : countsS;
    int* offs = blockIdx.x ? offsD : offsS;
    __shared__ int part[1024];
    int t = threadIdx.x;
    int base = t * 64;
    int s = 0;
    for (int i = 0; i < 64; ++i) s += counts[base + i];
    part[t] = s;
    __syncthreads();
    for (int off = 1; off < 1024; off <<= 1) {
        int v = part[t];
        int add = (t >= off) ? part[t - off] : 0;
        __syncthreads();
        part[t] = v + add;
        __syncthreads();
    }
    int run = (t == 0) ? 0 : part[t - 1];
    for (int i = 0; i < 64; ++i) { offs[base + i] = run; run += counts[base + i]; }
    if (t == 1023) offs[N_NODES] = run;
}

__global__ void inv_kernel(const int* __restrict__ countsD, float* __restrict__ inv) {
    int n = blockIdx.x * 256 + threadIdx.x;
    int c = countsD[n];
    inv[n] = (c > 0) ? (1.0f / (float)c) : 0.0f;
}

// src-sorted schedule: metaA[pS] = (src, attr*inv[dst], dstSlot, inv[dst])
__global__ void fill2_kernel(const int* __restrict__ src, const int* __restrict__ dst,
                             const float* __restrict__ attr, const int* __restrict__ offsS,
                             const int* __restrict__ offsD, const float* __restrict__ inv,
                             int* __restrict__ curS, int* __restrict__ curD,
                             int4* __restrict__ metaA) {
    int e = blockIdx.x * 256 + threadIdx.x;
    if (e >= N_EDGES) return;
    int s = src[e], d = dst[e];
    int pS = offsS[s] + atomicAdd(&curS[s], 1);
    int pD = offsD[d] + atomicAdd(&curD[d], 1);
    float iv = inv[d];
    metaA[pS] = make_int4(s, __float_as_int(attr[e] * iv), pD, __float_as_int(iv));
}

// ---------------- per-iteration kernels ----------------

// Pass A: src-sorted streaming gather of h rows (sequential-ish, ~4x row reuse),
// scattered fire-and-forget fp16 64B-row stores into dst-CSR slots. No chains.
__global__ __launch_bounds__(256, 8) void passA_kernel(
    const float* __restrict__ h, const int4* __restrict__ metaA,
    __half* __restrict__ msgH, __half* __restrict__ msgQ, const int* __restrict__ flag) {
    int t = threadIdx.x;
    int j = t & 31;
    int halfId = t >> 5;               // 0..7
    bool useB = (flag[0] != 0);
    int base = blockIdx.x * 128 + halfId * 16;
#pragma unroll 4
    for (int k = 0; k < 16; ++k) {
        int4 m = metaA[base + k];
        float hv = h[m.x * 32 + j];
        msgH[m.z * 32 + j] = __float2half(__int_as_float(m.y) * hv);
        if (useB) msgQ[m.z * 32 + j] = __float2half(__int_as_float(m.w) * hv);
    }
}

// Pass B: sequential segment reduction of msg rows per dst node, then node
// update hnew = h + relu(agg@V + h@root + bias) with float4-broadcast LDS
// matvecs. Half-wave owns 4 consecutive nodes (rows private per half).
__global__ __launch_bounds__(256, 8) void passB_kernel(
    float* __restrict__ h, const __half* __restrict__ msgH, const __half* __restrict__ msgQ,
    const int* __restrict__ offsD, const float* __restrict__ V, const float* __restrict__ Btot,
    const float* __restrict__ root, const float* __restrict__ bias, const int* __restrict__ flag) {
    __shared__ float Vl[1024], Rl[1024];
    __shared__ float hrow[32][32], arow[32][32];
    int t = threadIdx.x;
    bool useB = (flag[0] != 0);
    for (int i = t; i < 1024; i += 256) { Vl[i] = V[i]; Rl[i] = root[i]; }
    int j = t & 31;
    int halfId = t >> 5;               // 0..7, owns rows halfId*4 .. halfId*4+3
    int base = blockIdx.x * 32;
    float bj = bias[j];
    __syncthreads();
#pragma unroll
    for (int rr = 0; rr < 4; ++rr) {
        int ln = halfId * 4 + rr;
        int n = base + ln;
        int pb = offsD[n], pe = offsD[n + 1];
        float acc = 0.0f;
        int p = pb;
        for (; p + 1 < pe; p += 2)
            acc += __half2float(msgH[p * 32 + j]) + __half2float(msgH[(p + 1) * 32 + j]);
        if (p < pe) acc += __half2float(msgH[p * 32 + j]);
        float hv = h[n * 32 + j];
        hrow[ln][j] = hv;
        arow[ln][j] = acc;
        float u = bj;
#pragma unroll
        for (int i = 0; i < 32; i += 4) {
            float4 a4 = *(const float4*)&arow[ln][i];
            float4 h4 = *(const float4*)&hrow[ln][i];
            u += a4.x * Vl[i * 32 + j] + a4.y * Vl[(i + 1) * 32 + j]
               + a4.z * Vl[(i + 2) * 32 + j] + a4.w * Vl[(i + 3) * 32 + j]
               + h4.x * Rl[i * 32 + j] + h4.y * Rl[(i + 1) * 32 + j]
               + h4.z * Rl[(i + 2) * 32 + j] + h4.w * Rl[(i + 3) * 32 + j];
        }
        if (useB) {      // generality path (flag==0 for this input)
            float accq = 0.0f;
            for (p = pb; p < pe; ++p) accq += __half2float(msgQ[p * 32 + j]);
            arow[ln][j] = accq;
            for (int i = 0; i < 32; ++i) u += arow[ln][i] * Btot[i * 32 + j];
        }
        h[n * 32 + j] = hv + fmaxf(u, 0.0f);
    }
}

// ---------------- final reduction ----------------

__global__ void reduce_kernel(const float* __restrict__ h, float* __restrict__ gacc) {
    int j = threadIdx.x & 31, g = threadIdx.x >> 5;   // g: 0..7
    float s = 0.0f;
    int node0 = blockIdx.x * 128;
    for (int n = node0 + g; n < node0 + 128; n += 8) s += h[n * 32 + j];
    __shared__ float red[8][32];
    red[g][j] = s;
    __syncthreads();
    if (g == 0) {
        float tt = 0.0f;
        for (int k = 0; k < 8; ++k) tt += red[k][j];
        atomicAdd(&gacc[j], tt);
    }
}

__global__ void out_kernel(const float* __restrict__ gacc, const float* __restrict__ w,
                           const float* __restrict__ b, float* __restrict__ out) {
    if (threadIdx.x == 0) {
        float acc = 0.0f;
        for (int j = 0; j < 32; ++j) acc += gacc[j] * w[j];
        out[0] = acc * (1.0f / (float)N_NODES) + b[0];
    }
}

// ---------------- launch ----------------

extern "C" void kernel_launch(void* const* d_in, const int* in_sizes, int n_in,
                              void* d_out, int out_size, void* d_ws, size_t ws_size,
                              hipStream_t stream) {
    (void)in_sizes; (void)n_in; (void)out_size; (void)ws_size;
    const float* x        = (const float*)d_in[0];
    const int*   eidx     = (const int*)d_in[1];
    const float* eattr    = (const float*)d_in[2];
    const float* lin0_w   = (const float*)d_in[3];
    const float* lin0_b   = (const float*)d_in[4];
    const float* nn_w1    = (const float*)d_in[5];
    const float* nn_b1    = (const float*)d_in[6];
    const float* nn_w2    = (const float*)d_in[7];
    const float* nn_b2    = (const float*)d_in[8];
    const float* root     = (const float*)d_in[9];
    const float* conv_b   = (const float*)d_in[10];
    const float* lin2_w   = (const float*)d_in[11];
    const float* lin2_b   = (const float*)d_in[12];
    float* out = (float*)d_out;

    const int* src = eidx;
    const int* dst = eidx + N_EDGES;

    char* ws = (char*)d_ws;
    size_t off = 0;
    float*  h     = (float*)(ws + off);  off += (size_t)N_NODES * 32 * 4;    // 8 MB
    __half* msgH  = (__half*)(ws + off); off += (size_t)N_EDGES * 32 * 2;    // 16 MB
    __half* msgQ  = (__half*)(ws + off); off += (size_t)N_EDGES * 32 * 2;    // 16 MB
    float*  V     = (float*)(ws + off);  off += 4096;
    float*  Btot  = (float*)(ws + off);  off += 4096;
    float*  inv   = (float*)(ws + off);  off += (size_t)N_NODES * 4;
    int*    offsS = (int*)(ws + off);    off += 262400;                      // (N+1)*4 padded
    int*    offsD = (int*)(ws + off);    off += 262400;
    int4*   metaA = (int4*)(ws + off);   off += (size_t)N_EDGES * 16;        // 4 MB
    // zeroed region: countsS | countsD | curS | curD | gacc(32f) | flag
    char*   zbase   = ws + off;
    int*    countsS = (int*)zbase;
    int*    countsD = (int*)(zbase + (size_t)N_NODES * 4);
    int*    curS    = (int*)(zbase + (size_t)N_NODES * 8);
    int*    curD    = (int*)(zbase + (size_t)N_NODES * 12);
    float*  gacc    = (float*)(zbase + (size_t)N_NODES * 16);
    int*    flag    = (int*)(zbase + (size_t)N_NODES * 16 + 128);
    size_t  zsize   = (size_t)N_NODES * 16 + 256;

    hipMemsetAsync(zbase, 0, zsize, stream);

    vmat_kernel<<<4, 256, 0, stream>>>(nn_w1, nn_b1, nn_w2, nn_b2, V, Btot, flag);
    lin0_kernel<<<(N_NODES * 32) / 256, 256, 0, stream>>>(x, lin0_w, lin0_b, h);
    hist2_kernel<<<N_EDGES / 256, 256, 0, stream>>>(src, dst, countsS, countsD);
    scan2_kernel<<<2, 1024, 0, stream>>>(countsS, countsD, offsS, offsD);
    inv_kernel<<<N_NODES / 256, 256, 0, stream>>>(countsD, inv);
    fill2_kernel<<<N_EDGES / 256, 256, 0, stream>>>(src, dst, eattr, offsS, offsD, inv,
                                                    curS, curD, metaA);

    for (int it = 0; it < 8; ++it) {
        passA_kernel<<<N_EDGES / 128, 256, 0, stream>>>(h, metaA, msgH, msgQ, flag);
        passB_kernel<<<N_NODES / 32, 256, 0, stream>>>(h, msgH, msgQ, offsD, V, Btot,
                                                       root, conv_b, flag);
    }

    reduce_kernel<<<N_NODES / 128, 256, 0, stream>>>(h, gacc);
    out_kernel<<<1, 64, 0, stream>>>(gacc, lin2_w, lin2_b, out);
}

// Round 7
// 335.796 us; speedup vs baseline: 1.9373x; 1.0739x over previous
//
#include <hip/hip_runtime.h>

#define N_NODES 65536
#define N_EDGES 262144

// ---------------- setup kernels ----------------

// V[j] = sum_{k: w1[k]>0} w1[k]*w2[k][j];  Btot[j] = sum_{k: w1[k]>0} b1[k]*w2[k][j] + b2[j]
// exact linearization of relu(a*w1+b1)@w2+b2 for b1==0, a>=0.
__global__ void vmat_kernel(const float* __restrict__ w1, const float* __restrict__ b1,
                            const float* __restrict__ w2, const float* __restrict__ b2,
                            float* __restrict__ V, float* __restrict__ Btot, int* __restrict__ flag) {
    int j = blockIdx.x * 256 + threadIdx.x;        // 0..1023
    float v = 0.0f, c0 = 0.0f;
#pragma unroll
    for (int k = 0; k < 64; ++k) {
        float w = w1[k];
        if (w > 0.0f) {
            float wv = w2[k * 1024 + j];
            v += w * wv;
            c0 += b1[k] * wv;
        }
    }
    V[j] = v;
    float bt = c0 + b2[j];
    Btot[j] = bt;
    if (bt != 0.0f) atomicOr(flag, 1);
}

// h0 = relu(x @ lin0_w + lin0_b)
__global__ void lin0_kernel(const float* __restrict__ x, const float* __restrict__ w,
                            const float* __restrict__ b, float* __restrict__ h) {
    int idx = blockIdx.x * 256 + threadIdx.x;      // n*32+j
    int n = idx >> 5, j = idx & 31;
    float acc = b[j];
#pragma unroll
    for (int i = 0; i < 11; ++i) acc += x[n * 11 + i] * w[i * 32 + j];
    h[idx] = fmaxf(acc, 0.0f);
}

__global__ void hist_kernel(const int* __restrict__ dst, int* __restrict__ counts) {
    int e = blockIdx.x * 256 + threadIdx.x;
    if (e < N_EDGES) atomicAdd(&counts[dst[e]], 1);
}

// single-block exclusive scan of counts[65536] -> offs, offs[N]=E
__global__ void scan_kernel(const int* __restrict__ counts, int* __restrict__ offs) {
    __shared__ int part[1024];
    int t = threadIdx.x;
    int base = t * 64;
    int s = 0;
    for (int i = 0; i < 64; ++i) s += counts[base + i];
    part[t] = s;
    __syncthreads();
    for (int off = 1; off < 1024; off <<= 1) {
        int v = part[t];
        int add = (t >= off) ? part[t - off] : 0;
        __syncthreads();
        part[t] = v + add;
        __syncthreads();
    }
    int run = (t == 0) ? 0 : part[t - 1];
    for (int i = 0; i < 64; ++i) { offs[base + i] = run; run += counts[base + i]; }
    if (t == 1023) offs[N_NODES] = run;
}

__global__ void inv_kernel(const int* __restrict__ counts, float* __restrict__ inv) {
    int n = blockIdx.x * 256 + threadIdx.x;
    int c = counts[n];
    inv[n] = (c > 0) ? (1.0f / (float)c) : 0.0f;
}

// dst-CSR; rec = (src, attr*inv[dst]); qc = inv[dst] (generality path only)
__global__ void fill_kernel(const int* __restrict__ src, const int* __restrict__ dst,
                            const float* __restrict__ attr, const int* __restrict__ offs,
                            const float* __restrict__ inv, int* __restrict__ cursor,
                            int2* __restrict__ edgeRec, float* __restrict__ qc) {
    int e = blockIdx.x * 256 + threadIdx.x;
    if (e >= N_EDGES) return;
    int d = dst[e];
    int p = offs[d] + atomicAdd(&cursor[d], 1);
    edgeRec[p] = make_int2(src[e], __float_as_int(attr[e] * inv[d]));
    qc[p] = inv[d];
}

// ---------------- per-iteration kernel ----------------
// One dst node per HALF-WAVE: its ~4 gathers issue independently (4-wide
// batch, min-clamp masking, register accumulation — no atomics, no serial
// multi-node chain). agg@V is applied AFTER aggregation (linear), so gathers
// read h directly — no P/Q tables. h double-buffered (gather source != dst).
// __syncthreads for Vl/Rl staging deferred until after the edge loop (edge
// phase touches no LDS) so staging latency hides under the gathers.
__global__ __launch_bounds__(256, 8) void iter2_kernel(
    const float* __restrict__ hin, float* __restrict__ hout,
    const int* __restrict__ offs, const int2* __restrict__ edgeRec,
    const float* __restrict__ qc, const float* __restrict__ V,
    const float* __restrict__ Btot, const float* __restrict__ root,
    const float* __restrict__ bias, const int* __restrict__ flag) {
    __shared__ float Vl[1024], Rl[1024];
    __shared__ float hrow[8][32], arow[8][32];
    int t = threadIdx.x;
    bool useB = (flag[0] != 0);
    for (int i = t; i < 1024; i += 256) { Vl[i] = V[i]; Rl[i] = root[i]; }
    int j = t & 31, hs = t >> 5;               // half-wave slot 0..7
    int n = blockIdx.x * 8 + hs;
    float bj = bias[j];
    int pb = offs[n], pe = offs[n + 1];
    float hv = hin[n * 32 + j];                // own row, independent load
    float facc = 0.0f, faccB = 0.0f;
    for (int p = pb; p < pe; p += 4) {
#pragma unroll
        for (int k = 0; k < 4; ++k) {
            int idx = p + k;
            int2 r = edgeRec[min(idx, pe - 1)];
            float g = hin[r.x * 32 + j];
            float m = __int_as_float(r.y) * g;
            facc += (idx < pe) ? m : 0.0f;
            if (useB) faccB += (idx < pe) ? qc[idx] * g : 0.0f;
        }
    }
    __syncthreads();                           // Vl/Rl ready
    hrow[hs][j] = hv;
    arow[hs][j] = facc;
    float u = bj;
#pragma unroll
    for (int i = 0; i < 32; i += 4) {
        float4 a4 = *(const float4*)&arow[hs][i];
        float4 h4 = *(const float4*)&hrow[hs][i];
        u += a4.x * Vl[i * 32 + j] + a4.y * Vl[(i + 1) * 32 + j]
           + a4.z * Vl[(i + 2) * 32 + j] + a4.w * Vl[(i + 3) * 32 + j]
           + h4.x * Rl[i * 32 + j] + h4.y * Rl[(i + 1) * 32 + j]
           + h4.z * Rl[(i + 2) * 32 + j] + h4.w * Rl[(i + 3) * 32 + j];
    }
    if (useB) {                                // generality path (flag==0 here)
        arow[hs][j] = faccB;
        for (int i = 0; i < 32; ++i) u += arow[hs][i] * Btot[i * 32 + j];
    }
    hout[n * 32 + j] = hv + fmaxf(u, 0.0f);
}

// ---------------- final reduction ----------------

__global__ void reduce_kernel(const float* __restrict__ h, float* __restrict__ gacc) {
    int j = threadIdx.x & 31, g = threadIdx.x >> 5;   // g: 0..7
    float s = 0.0f;
    int node0 = blockIdx.x * 128;
    for (int n = node0 + g; n < node0 + 128; n += 8) s += h[n * 32 + j];
    __shared__ float red[8][32];
    red[g][j] = s;
    __syncthreads();
    if (g == 0) {
        float tt = 0.0f;
        for (int k = 0; k < 8; ++k) tt += red[k][j];
        atomicAdd(&gacc[j], tt);
    }
}

__global__ void out_kernel(const float* __restrict__ gacc, const float* __restrict__ w,
                           const float* __restrict__ b, float* __restrict__ out) {
    if (threadIdx.x == 0) {
        float acc = 0.0f;
        for (int j = 0; j < 32; ++j) acc += gacc[j] * w[j];
        out[0] = acc * (1.0f / (float)N_NODES) + b[0];
    }
}

// ---------------- launch ----------------

extern "C" void kernel_launch(void* const* d_in, const int* in_sizes, int n_in,
                              void* d_out, int out_size, void* d_ws, size_t ws_size,
                              hipStream_t stream) {
    (void)in_sizes; (void)n_in; (void)out_size; (void)ws_size;
    const float* x        = (const float*)d_in[0];
    const int*   eidx     = (const int*)d_in[1];
    const float* eattr    = (const float*)d_in[2];
    const float* lin0_w   = (const float*)d_in[3];
    const float* lin0_b   = (const float*)d_in[4];
    const float* nn_w1    = (const float*)d_in[5];
    const float* nn_b1    = (const float*)d_in[6];
    const float* nn_w2    = (const float*)d_in[7];
    const float* nn_b2    = (const float*)d_in[8];
    const float* root     = (const float*)d_in[9];
    const float* conv_b   = (const float*)d_in[10];
    const float* lin2_w   = (const float*)d_in[11];
    const float* lin2_b   = (const float*)d_in[12];
    float* out = (float*)d_out;

    const int* src = eidx;
    const int* dst = eidx + N_EDGES;

    char* ws = (char*)d_ws;
    size_t off = 0;
    float* hA   = (float*)(ws + off); off += (size_t)N_NODES * 32 * 4;   // 8 MB
    float* hB   = (float*)(ws + off); off += (size_t)N_NODES * 32 * 4;   // 8 MB
    float* V    = (float*)(ws + off); off += 4096;
    float* Btot = (float*)(ws + off); off += 4096;
    float* inv  = (float*)(ws + off); off += (size_t)N_NODES * 4;
    int*   offs = (int*)(ws + off);   off += 262400;                     // (N+1)*4 padded
    int2*  edgeRec = (int2*)(ws + off); off += (size_t)N_EDGES * 8;      // 2 MB
    float* qc   = (float*)(ws + off); off += (size_t)N_EDGES * 4;        // 1 MB
    // zeroed region: counts | cursor | gacc(32f) | flag
    char*  zbase  = ws + off;
    int*   counts = (int*)zbase;
    int*   cursor = (int*)(zbase + (size_t)N_NODES * 4);
    float* gacc   = (float*)(zbase + (size_t)N_NODES * 8);
    int*   flag   = (int*)(zbase + (size_t)N_NODES * 8 + 128);
    size_t zsize  = (size_t)N_NODES * 8 + 256;

    hipMemsetAsync(zbase, 0, zsize, stream);

    vmat_kernel<<<4, 256, 0, stream>>>(nn_w1, nn_b1, nn_w2, nn_b2, V, Btot, flag);
    lin0_kernel<<<(N_NODES * 32) / 256, 256, 0, stream>>>(x, lin0_w, lin0_b, hA);
    hist_kernel<<<N_EDGES / 256, 256, 0, stream>>>(dst, counts);
    scan_kernel<<<1, 1024, 0, stream>>>(counts, offs);
    inv_kernel<<<N_NODES / 256, 256, 0, stream>>>(counts, inv);
    fill_kernel<<<N_EDGES / 256, 256, 0, stream>>>(src, dst, eattr, offs, inv, cursor, edgeRec, qc);

    float* hbuf[2] = {hA, hB};
    for (int it = 0; it < 8; ++it) {
        iter2_kernel<<<N_NODES / 8, 256, 0, stream>>>(
            hbuf[it & 1], hbuf[(it + 1) & 1], offs, edgeRec, qc, V, Btot, root, conv_b, flag);
    }

    reduce_kernel<<<N_NODES / 128, 256, 0, stream>>>(hA, gacc);   // after 8 iters result is in hA
    out_kernel<<<1, 64, 0, stream>>>(gacc, lin2_w, lin2_b, out);
}